// Round 1
// baseline (160.004 us; speedup 1.0000x reference)
//
#include <hip/hip_runtime.h>
#include <hip/hip_bf16.h>
#include <math.h>

// Problem constants (from reference)
#define BB 16
#define LL 2048
#define ED 64
#define NN 32
#define KK 16
#define NCHUNK 32
#define CH 64          // steps per chunk (LL / NCHUNK)
#define T1 64          // tokens per featurize tile

// -------------------- Kernel 1: featurize --------------------
// Per block: one batch b, one tile of 64 tokens (+15 halo).
// Computes xb (post conv+silu), dtr scalar, Bm; z/C only at l=L-1.
__global__ __launch_bounds__(256) void k1_feat(
    const float* __restrict__ x, const float* __restrict__ norm_w,
    const float* __restrict__ w_in, const float* __restrict__ conv_w,
    const float* __restrict__ conv_b, const float* __restrict__ w_xproj,
    float* __restrict__ xbuf, float* __restrict__ dtrbuf,
    float* __restrict__ bbuf, float* __restrict__ z_last,
    float* __restrict__ c_last)
{
    const int b = blockIdx.y;
    const int tile = blockIdx.x;           // 0..31
    const int l0 = tile * T1;
    const int tid = threadIdx.x;

    __shared__ float pre[T1 + KK - 1][ED]; // pre-conv xb, with 15-token halo
    __shared__ float xbl[T1][ED];          // post conv+silu

    // Stage pre-conv activations (rmsnorm -> w_in cols 0..63)
    for (int idx = tid; idx < (T1 + KK - 1) * ED; idx += 256) {
        int p = idx >> 6, e = idx & 63;
        int l = l0 - (KK - 1) + p;
        float v = 0.f;
        if (l >= 0) {
            float x0 = x[(b * LL + l) * 2 + 0];
            float x1 = x[(b * LL + l) * 2 + 1];
            float s = rsqrtf(0.5f * (x0 * x0 + x1 * x1) + 1e-5f);
            float h0 = x0 * s * norm_w[0];
            float h1 = x1 * s * norm_w[1];
            v = h0 * w_in[e] + h1 * w_in[128 + e];
            if (l == LL - 1) {
                // z branch (cols 64..127), only needed at last token
                float zv = h0 * w_in[64 + e] + h1 * w_in[128 + 64 + e];
                z_last[b * ED + e] = zv;
            }
        }
        pre[p][e] = v;
    }
    __syncthreads();

    // Depthwise causal conv (K=16) + bias + silu
    for (int idx = tid; idx < T1 * ED; idx += 256) {
        int t = idx >> 6, e = idx & 63;
        float acc = conv_b[e];
        #pragma unroll
        for (int k = 0; k < KK; ++k)
            acc = __fmaf_rn(conv_w[e * KK + k], pre[t + k][e], acc);
        float sig = 1.f / (1.f + __expf(-acc));
        float xb = acc * sig;
        xbl[t][e] = xb;
        xbuf[(b * LL + l0 + t) * ED + e] = xb;
    }
    __syncthreads();

    // xproj: dbc[t][j] = sum_e xb[t][e] * w_xproj[e*65 + j]
    for (int idx = tid; idx < T1 * 64; idx += 256) {
        int t = idx >> 6, j = idx & 63;
        float acc = 0.f;
        #pragma unroll 8
        for (int e = 0; e < ED; ++e)
            acc = __fmaf_rn(xbl[t][e], w_xproj[e * 65 + j], acc);
        int l = l0 + t;
        if (j == 0) {
            dtrbuf[b * LL + l] = acc;               // delta raw scalar
        } else if (j <= 32) {
            bbuf[(b * LL + l) * NN + (j - 1)] = acc; // Bm
        } else if (l == LL - 1) {
            c_last[b * NN + (j - 33)] = acc;         // C (n = 0..30)
        }
    }
    // j == 64 column -> C[n=31], only at last token
    if (tid < T1) {
        int t = tid, l = l0 + t;
        if (l == LL - 1) {
            float acc = 0.f;
            for (int e = 0; e < ED; ++e)
                acc = __fmaf_rn(xbl[t][e], w_xproj[e * 65 + 64], acc);
            c_last[b * NN + 31] = acc;
        }
    }
}

// -------------------- Kernel 2: chunked scan --------------------
// Block = (chunk c, batch b). 256 threads: e = tid&63, n-group = tid>>6 (8 n each).
// Computes chunk transfer (P = prod dA, S = chunk-local final state).
__global__ __launch_bounds__(256) void k2_scan(
    const float* __restrict__ xbuf, const float* __restrict__ dtrbuf,
    const float* __restrict__ bbuf, const float* __restrict__ w_dt,
    const float* __restrict__ b_dt, const float* __restrict__ A_log,
    float* __restrict__ pbuf, float* __restrict__ sbuf)
{
    const int b = blockIdx.y;
    const int c = blockIdx.x;              // 0..NCHUNK-1
    const int l0 = c * CH;
    const int tid = threadIdx.x;
    const int e = tid & 63, ng = tid >> 6, n0 = ng * 8;

    __shared__ float dl[CH][ED];   // delta[s][e] (after softplus)
    __shared__ float xbl[CH][ED];  // xb[s][e]
    __shared__ float bml[CH][NN];  // Bm[s][n]
    __shared__ float dtr_s[CH];

    if (tid < CH) dtr_s[tid] = dtrbuf[b * LL + l0 + tid];
    __syncthreads();

    for (int idx = tid; idx < CH * ED; idx += 256) {
        int s = idx >> 6, ee = idx & 63;
        float v = __fmaf_rn(dtr_s[s], w_dt[ee], b_dt[ee]);
        dl[s][ee] = (v > 15.f) ? v : log1pf(__expf(v));   // softplus
        xbl[s][ee] = xbuf[(b * LL + l0 + s) * ED + ee];
    }
    for (int idx = tid; idx < CH * NN; idx += 256) {
        int s = idx >> 5, nn = idx & 31;
        bml[s][nn] = bbuf[(b * LL + l0 + s) * NN + nn];
    }
    __syncthreads();

    float A[8], P[8], S[8];
    #pragma unroll
    for (int j = 0; j < 8; ++j) {
        A[j] = -__expf(A_log[e * NN + n0 + j]);
        P[j] = 1.f;
        S[j] = 0.f;
    }

    for (int s = 0; s < CH; ++s) {
        float d  = dl[s][e];
        float xv = xbl[s][e];
        float dx = d * xv;
        #pragma unroll
        for (int j = 0; j < 8; ++j) {
            float dA = __expf(d * A[j]);
            P[j] *= dA;
            S[j] = __fmaf_rn(dA, S[j], dx * bml[s][n0 + j]);
        }
    }

    int base = (c * BB + b) * (ED * NN) + e * NN + n0;
    #pragma unroll
    for (int j = 0; j < 8; ++j) {
        pbuf[base + j] = P[j];
        sbuf[base + j] = S[j];
    }
}

// -------------------- Kernel 3: combine chunks --------------------
// h_final[b,e,n] = fold over chunks in order: h = P_c*h + S_c (h starts 0).
__global__ __launch_bounds__(256) void k3_combine(
    const float* __restrict__ pbuf, const float* __restrict__ sbuf,
    float* __restrict__ hfin)
{
    int idx = blockIdx.x * 256 + threadIdx.x;   // 0 .. B*ED*NN-1 (32768)
    float h = 0.f;
    #pragma unroll 4
    for (int c = 0; c < NCHUNK; ++c) {
        int o = c * (BB * ED * NN) + idx;
        h = __fmaf_rn(pbuf[o], h, sbuf[o]);
    }
    hfin[idx] = h;
}

// -------------------- Kernel 4: epilogue (per batch) --------------------
__global__ __launch_bounds__(256) void k4_epilogue(
    const float* __restrict__ hfin, const float* __restrict__ c_last,
    const float* __restrict__ z_last, const float* __restrict__ xbuf,
    const float* __restrict__ D_skip, const float* __restrict__ w_out,
    const float* __restrict__ b_out, const float* __restrict__ w_fc,
    const float* __restrict__ b_fc, const float* __restrict__ w_cls,
    const float* __restrict__ b_cls, const float* __restrict__ w_reg,
    const float* __restrict__ b_reg, float* __restrict__ out)
{
    int b = blockIdx.x;
    int tid = threadIdx.x;
    int e = tid & 63, ng = tid >> 6, n0 = ng * 8;

    __shared__ float part[4][ED];
    __shared__ float ylds[ED];
    __shared__ float olds[ED];
    __shared__ float hlds[ED];

    // y_e = sum_n h[e,n] * C_last[n]
    float acc = 0.f;
    #pragma unroll
    for (int j = 0; j < 8; ++j)
        acc = __fmaf_rn(hfin[b * (ED * NN) + e * NN + n0 + j],
                        c_last[b * NN + n0 + j], acc);
    part[ng][e] = acc;
    __syncthreads();

    if (tid < ED) {
        float y = part[0][e] + part[1][e] + part[2][e] + part[3][e];
        y = __fmaf_rn(D_skip[e], xbuf[(b * LL + LL - 1) * ED + e], y);
        float z = z_last[b * ED + e];
        y *= z / (1.f + __expf(-z));          // y * silu(z)
        ylds[e] = y;
    }
    __syncthreads();

    if (tid < ED) {
        float a2 = b_out[tid];
        #pragma unroll 8
        for (int ee = 0; ee < ED; ++ee)
            a2 = __fmaf_rn(ylds[ee], w_out[ee * ED + tid], a2);
        olds[tid] = a2;
    }
    __syncthreads();

    if (tid < ED) {
        float a3 = b_fc[tid];
        #pragma unroll 8
        for (int ee = 0; ee < ED; ++ee)
            a3 = __fmaf_rn(olds[ee], w_fc[ee * ED + tid], a3);
        hlds[tid] = fmaxf(a3, 0.f);
    }
    __syncthreads();

    if (tid < 4) {
        float a4 = b_cls[tid];
        for (int ee = 0; ee < ED; ++ee)
            a4 = __fmaf_rn(hlds[ee], w_cls[ee * 4 + tid], a4);
        out[b * 4 + tid] = a4;                 // class_logits, row-major (B,4)
    } else if (tid == 4) {
        float a5 = b_reg[0];
        for (int ee = 0; ee < ED; ++ee)
            a5 = __fmaf_rn(hlds[ee], w_reg[ee], a5);
        out[BB * 4 + b] = a5;                  // mass_pred
    }
}

extern "C" void kernel_launch(void* const* d_in, const int* in_sizes, int n_in,
                              void* d_out, int out_size, void* d_ws, size_t ws_size,
                              hipStream_t stream) {
    const float* x       = (const float*)d_in[0];
    const float* norm_w  = (const float*)d_in[1];
    const float* w_in    = (const float*)d_in[2];
    const float* conv_w  = (const float*)d_in[3];
    const float* conv_b  = (const float*)d_in[4];
    const float* w_xproj = (const float*)d_in[5];
    const float* w_dt    = (const float*)d_in[6];
    const float* b_dt    = (const float*)d_in[7];
    const float* A_log   = (const float*)d_in[8];
    const float* D_skip  = (const float*)d_in[9];
    const float* w_out   = (const float*)d_in[10];
    const float* b_out   = (const float*)d_in[11];
    const float* w_fc    = (const float*)d_in[12];
    const float* b_fc    = (const float*)d_in[13];
    const float* w_cls   = (const float*)d_in[14];
    const float* b_cls   = (const float*)d_in[15];
    const float* w_reg   = (const float*)d_in[16];
    const float* b_reg   = (const float*)d_in[17];
    float* out = (float*)d_out;

    // Workspace layout (floats)
    float* ws     = (float*)d_ws;
    float* xbuf   = ws;                         // B*L*ED        = 2,097,152
    float* dtrbuf = xbuf + BB * LL * ED;        // B*L           = 32,768
    float* bbuf   = dtrbuf + BB * LL;           // B*L*NN        = 1,048,576
    float* pbuf   = bbuf + BB * LL * NN;        // NCHUNK*B*ED*NN= 1,048,576
    float* sbuf   = pbuf + NCHUNK * BB * ED * NN;
    float* hfin   = sbuf + NCHUNK * BB * ED * NN; // B*ED*NN     = 32,768
    float* zl     = hfin + BB * ED * NN;        // B*ED          = 1,024
    float* cl     = zl + BB * ED;               // B*NN          = 512

    dim3 g1(LL / T1, BB);
    k1_feat<<<g1, 256, 0, stream>>>(x, norm_w, w_in, conv_w, conv_b, w_xproj,
                                    xbuf, dtrbuf, bbuf, zl, cl);

    dim3 g2(NCHUNK, BB);
    k2_scan<<<g2, 256, 0, stream>>>(xbuf, dtrbuf, bbuf, w_dt, b_dt, A_log,
                                    pbuf, sbuf);

    k3_combine<<<(BB * ED * NN) / 256, 256, 0, stream>>>(pbuf, sbuf, hfin);

    k4_epilogue<<<BB, 256, 0, stream>>>(hfin, cl, zl, xbuf, D_skip,
                                        w_out, b_out, w_fc, b_fc,
                                        w_cls, b_cls, w_reg, b_reg, out);
}